// Round 6
// baseline (1005.536 us; speedup 1.0000x reference)
//
#include <hip/hip_runtime.h>
#include <hip/hip_bf16.h>
#include <math.h>

typedef __attribute__((ext_vector_type(4))) float floatx4;
typedef __attribute__((ext_vector_type(8))) __bf16 bfloatx8;
typedef __attribute__((ext_vector_type(8))) unsigned short ushortx8;

static __device__ __forceinline__ unsigned short f2bf(float f) {
  __hip_bfloat16 h = __float2bfloat16(f);
  return *reinterpret_cast<unsigned short*>(&h);
}

static __device__ __forceinline__ void gload16(const void* g, void* l) {
  __builtin_amdgcn_global_load_lds(
      (const __attribute__((address_space(1))) unsigned int*)g,
      (__attribute__((address_space(3))) unsigned int*)l, 16, 0, 0);
}

#define S_BARRIER() __builtin_amdgcn_s_barrier()
#define WAIT_LGKM0() do { asm volatile("s_waitcnt lgkmcnt(0)" ::: "memory"); __builtin_amdgcn_sched_barrier(0); } while (0)
#define WAIT_VM(n)   do { asm volatile("s_waitcnt vmcnt(" #n ")" ::: "memory"); __builtin_amdgcn_sched_barrier(0); } while (0)

// ---------------- x: f32 -> bf16 ----------------
__global__ __launch_bounds__(256) void convert_x_kernel(const float4* __restrict__ in,
                                                        ushort4* __restrict__ out) {
  int i = blockIdx.x * 256 + threadIdx.x;
  float4 v = in[i];
  ushort4 o;
  o.x = f2bf(v.x); o.y = f2bf(v.y); o.z = f2bf(v.z); o.w = f2bf(v.w);
  out[i] = o;
}

// ------------- transpose + cast: out[c][r] = bf16(in[r][c]) -------------
__global__ __launch_bounds__(256) void transpose_bf16_kernel(const float* __restrict__ in,
                                                             unsigned short* __restrict__ out,
                                                             int rows, int cols) {
  __shared__ float tile[32][33];
  int c0 = blockIdx.x * 32, r0 = blockIdx.y * 32;
  int tx = threadIdx.x, ty = threadIdx.y;
#pragma unroll
  for (int j = 0; j < 32; j += 8)
    tile[ty + j][tx] = in[(size_t)(r0 + ty + j) * cols + c0 + tx];
  __syncthreads();
#pragma unroll
  for (int j = 0; j < 32; j += 8)
    out[(size_t)(c0 + ty + j) * rows + r0 + tx] = f2bf(tile[tx][ty + j]);
}

// ------------- lora_mid[m][r] = sum_k x[m][k] * a_down[idx][k][r] -------------
__global__ __launch_bounds__(256) void lora_mid_kernel(const float* __restrict__ x,
                                                       const float* __restrict__ a_down,
                                                       const int* __restrict__ idxp,
                                                       float* __restrict__ lmid) {
  __shared__ float ad[1024 * 9];
  const float* A = a_down + (size_t)(*idxp) * (1024 * 8);
  int t = threadIdx.x;
  for (int i = t; i < 8192; i += 256) ad[(i >> 3) * 9 + (i & 7)] = A[i];
  __syncthreads();
  int wid = t >> 6, lane = t & 63;
  int row = blockIdx.x * 4 + wid;
  const float* xr = x + (size_t)row * 1024;
  float acc[8] = {0.f, 0.f, 0.f, 0.f, 0.f, 0.f, 0.f, 0.f};
  for (int i = 0; i < 16; ++i) {
    int k = i * 64 + lane;
    float xv = xr[k];
#pragma unroll
    for (int r = 0; r < 8; ++r) acc[r] += xv * ad[k * 9 + r];
  }
#pragma unroll
  for (int off = 32; off > 0; off >>= 1) {
#pragma unroll
    for (int r = 0; r < 8; ++r) acc[r] += __shfl_xor(acc[r], off);
  }
  if (lane == 0) {
    *(float4*)(lmid + (size_t)row * 8) = make_float4(acc[0], acc[1], acc[2], acc[3]);
    *(float4*)(lmid + (size_t)row * 8 + 4) = make_float4(acc[4], acc[5], acc[6], acc[7]);
  }
}

// ================= 256x256 8-phase K-loop, whole-tile staged pipeline =================
// (BK=64, 8 waves 2Mx4N, 128 KiB LDS dbuf.) Phase order per tile: (MH,NH)=(0,0)(0,1)(1,1)(1,0);
// both B fragment sets stay in registers (bq0,bq1) so phase 4 has no ds_read.
//
// CRITICAL read decomposition (round-5 bug): wm=1 waves read A rows 128-255 and wn=2,3 waves
// read B rows 128-255, so EVERY A-load phase touches BOTH A stage-halves and every B-load
// phase touches BOTH B halves. Hence a tile's ALL FOUR stage-groups (8 loads) must be drained
// before its FIRST compute phase. Whole-tile staging + whole-tile draining:
//   reads:  P1: b0.A(both halves)+b0.B(both)   P2: b0.B(both)   P3: b0.A(both)   P4: regs only
//           P5-P8: same on b1.
//   quiet:  b0.B after P2-close, b0.A after P3-close, b1.B after P6-close, b1.A after P7-close.
//   stages: P3: B0+B1(u0)->b0   P4: A0+A1(u0)->b0   P7: B0+B1(u1)->b1   P8: A0+A1(u1)->b1
//   waits:  end-P4 vmcnt(8)  (drains ALL of t1; leaves u0's 8)   -> P5 reads t1 safely
//           end-P8 vmcnt(8)  (drains ALL of u0; leaves u1's 8)   -> next-P1 reads u0 safely
// FIFO invariant at P1 entry: 8 outstanding = next tile's loads. Issue->drain lead: 4-5 phases
// (~1000+ cyc >= HBM latency). Prologue stages t0+t1 (16 loads), vmcnt(8) drains t0.
template <int LDA, int LDB, int NKT>
static __device__ __forceinline__ void kloop8(const unsigned short* __restrict__ A,
                                              const unsigned short* __restrict__ B,
                                              size_t m0, size_t n0, char* smem,
                                              floatx4 (&acc)[8][4]) {
  const int t = threadIdx.x;
  const int wid = t >> 6, lane = t & 63;
  const int wm = wid >> 2, wn = wid & 3;
  const int lr = lane & 15, kg = lane >> 4;
  const unsigned lxor = (unsigned)(lane & 7) << 4;
  const unsigned aRd = ((unsigned)(wm * 128 + lr) << 7) + ((unsigned)kg << 4);
  const unsigned bRd = 32768u + ((unsigned)(wn * 64 + lr) << 7) + ((unsigned)kg << 4);
  const int srow = t >> 3;
  const int scol = ((t & 7) ^ ((t >> 3) & 7)) << 3;  // elements (pre-swizzled source col)
  const unsigned short* sA = A + (m0 + (size_t)srow) * LDA + scol;
  const unsigned short* sB = B + (n0 + (size_t)srow) * LDB + scol;
  const unsigned ldsW = (unsigned)(wid << 10);

#define STG_A(tau, h, bufb)                                                            \
  do {                                                                                 \
    unsigned lo_ = (bufb) + (unsigned)(h)*16384u + ldsW;                               \
    gload16(sA + (size_t)((h)*128) * LDA + (size_t)(tau)*64, smem + lo_);              \
    gload16(sA + (size_t)((h)*128 + 64) * LDA + (size_t)(tau)*64, smem + lo_ + 8192);  \
  } while (0)
#define STG_B(tau, h, bufb)                                                            \
  do {                                                                                 \
    unsigned lo_ = (bufb) + 32768u + (unsigned)(h)*16384u + ldsW;                      \
    gload16(sB + (size_t)((h)*128) * LDB + (size_t)(tau)*64, smem + lo_);              \
    gload16(sB + (size_t)((h)*128 + 64) * LDB + (size_t)(tau)*64, smem + lo_ + 8192);  \
  } while (0)

  bfloatx8 af[4][2], bq0[2][2], bq1[2][2];
#define LOAD_A(bufb, MH)                                                                          \
  do {                                                                                            \
    _Pragma("unroll") for (int mi = 0; mi < 4; ++mi)                                              \
        _Pragma("unroll") for (int ks = 0; ks < 2; ++ks)                                          \
            af[mi][ks] = *(const bfloatx8*)(smem +                                                \
                (((bufb) + aRd + (unsigned)(MH)*8192u + (unsigned)mi * 2048u + (unsigned)ks * 64u) ^ lxor)); \
  } while (0)
#define LOAD_B0(bufb)                                                                             \
  do {                                                                                            \
    _Pragma("unroll") for (int ni = 0; ni < 2; ++ni)                                              \
        _Pragma("unroll") for (int ks = 0; ks < 2; ++ks)                                          \
            bq0[ni][ks] = *(const bfloatx8*)(smem +                                               \
                (((bufb) + bRd + (unsigned)ni * 2048u + (unsigned)ks * 64u) ^ lxor));             \
  } while (0)
#define LOAD_B1(bufb)                                                                             \
  do {                                                                                            \
    _Pragma("unroll") for (int ni = 0; ni < 2; ++ni)                                              \
        _Pragma("unroll") for (int ks = 0; ks < 2; ++ks)                                          \
            bq1[ni][ks] = *(const bfloatx8*)(smem +                                               \
                (((bufb) + bRd + 4096u + (unsigned)ni * 2048u + (unsigned)ks * 64u) ^ lxor));     \
  } while (0)
#define MFMA_B0(MH)                                                                               \
  do {                                                                                            \
    __builtin_amdgcn_s_setprio(1);                                                                \
    _Pragma("unroll") for (int mi = 0; mi < 4; ++mi)                                              \
        _Pragma("unroll") for (int ni = 0; ni < 2; ++ni)                                          \
            _Pragma("unroll") for (int ks = 0; ks < 2; ++ks)                                      \
                acc[(MH)*4 + mi][ni] = __builtin_amdgcn_mfma_f32_16x16x32_bf16(                   \
                    af[mi][ks], bq0[ni][ks], acc[(MH)*4 + mi][ni], 0, 0, 0);                      \
    __builtin_amdgcn_s_setprio(0);                                                                \
  } while (0)
#define MFMA_B1(MH)                                                                               \
  do {                                                                                            \
    __builtin_amdgcn_s_setprio(1);                                                                \
    _Pragma("unroll") for (int mi = 0; mi < 4; ++mi)                                              \
        _Pragma("unroll") for (int ni = 0; ni < 2; ++ni)                                          \
            _Pragma("unroll") for (int ks = 0; ks < 2; ++ks)                                      \
                acc[(MH)*4 + mi][2 + ni] = __builtin_amdgcn_mfma_f32_16x16x32_bf16(               \
                    af[mi][ks], bq1[ni][ks], acc[(MH)*4 + mi][2 + ni], 0, 0, 0);                  \
    __builtin_amdgcn_s_setprio(0);                                                                \
  } while (0)

  // prologue: whole tile0 -> buf0, whole tile1 -> buf1 (16 loads); drain tile0 (leave tile1's 8)
  STG_B(0, 0, 0u); STG_B(0, 1, 0u); STG_A(0, 0, 0u); STG_A(0, 1, 0u);
  STG_B(1, 0, 65536u); STG_B(1, 1, 65536u); STG_A(1, 0, 65536u); STG_A(1, 1, 65536u);
  WAIT_VM(8);
  S_BARRIER();

  const int nit = NKT / 2;
#pragma unroll 1
  for (int it = 0; it < nit - 1; ++it) {
    const int u0 = 2 * it + 2, u1 = 2 * it + 3;
    // P1 (0,0) on buf0
    LOAD_A(0u, 0); LOAD_B0(0u);
    S_BARRIER(); WAIT_LGKM0(); MFMA_B0(0); S_BARRIER();
    // P2 (0,1)
    LOAD_B1(0u);
    S_BARRIER(); WAIT_LGKM0(); MFMA_B1(0); S_BARRIER();
    // P3 (1,1)  — buf0.B quiet (last read P2): stage B(u0)
    LOAD_A(0u, 1); STG_B(u0, 0, 0u); STG_B(u0, 1, 0u);
    S_BARRIER(); WAIT_LGKM0(); MFMA_B1(1); S_BARRIER();
    // P4 (1,0)  — buf0.A quiet (last read P3): stage A(u0); drain ALL of tile t1
    STG_A(u0, 0, 0u); STG_A(u0, 1, 0u);
    S_BARRIER(); MFMA_B0(1); WAIT_VM(8); S_BARRIER();
    // P5 (0,0) on buf1
    LOAD_A(65536u, 0); LOAD_B0(65536u);
    S_BARRIER(); WAIT_LGKM0(); MFMA_B0(0); S_BARRIER();
    // P6 (0,1)
    LOAD_B1(65536u);
    S_BARRIER(); WAIT_LGKM0(); MFMA_B1(0); S_BARRIER();
    // P7 (1,1)  — buf1.B quiet: stage B(u1)
    LOAD_A(65536u, 1); STG_B(u1, 0, 65536u); STG_B(u1, 1, 65536u);
    S_BARRIER(); WAIT_LGKM0(); MFMA_B1(1); S_BARRIER();
    // P8 (1,0)  — buf1.A quiet: stage A(u1); drain ALL of tile u0
    STG_A(u1, 0, 65536u); STG_A(u1, 1, 65536u);
    S_BARRIER(); MFMA_B0(1); WAIT_VM(8); S_BARRIER();
  }
  {  // tail: tiles NKT-2 (buf0), NKT-1 (buf1); no stages; drain remaining 8 at end-P4
    LOAD_A(0u, 0); LOAD_B0(0u);
    S_BARRIER(); WAIT_LGKM0(); MFMA_B0(0); S_BARRIER();
    LOAD_B1(0u);
    S_BARRIER(); WAIT_LGKM0(); MFMA_B1(0); S_BARRIER();
    LOAD_A(0u, 1);
    S_BARRIER(); WAIT_LGKM0(); MFMA_B1(1); S_BARRIER();
    S_BARRIER(); MFMA_B0(1); WAIT_VM(0); S_BARRIER();
    LOAD_A(65536u, 0); LOAD_B0(65536u);
    S_BARRIER(); WAIT_LGKM0(); MFMA_B0(0); S_BARRIER();
    LOAD_B1(65536u);
    S_BARRIER(); WAIT_LGKM0(); MFMA_B1(0); S_BARRIER();
    LOAD_A(65536u, 1);
    S_BARRIER(); WAIT_LGKM0(); MFMA_B1(1); S_BARRIER();
    S_BARRIER(); MFMA_B0(1); S_BARRIER();
  }
#undef MFMA_B1
#undef MFMA_B0
#undef LOAD_B1
#undef LOAD_B0
#undef LOAD_A
#undef STG_B
#undef STG_A
}

// ------------- GEMM1: H = gelu(Xb @ W1T^T + b1), bf16 out. M=16384 N=4096 K=1024 -------------
__global__ __launch_bounds__(512, 2) void gemm1_8ph(const unsigned short* __restrict__ A,
                                                    const unsigned short* __restrict__ B,
                                                    const float* __restrict__ bias,
                                                    unsigned short* __restrict__ H) {
  extern __shared__ char smem[];
  const int nwg = 1024;
  int bid = blockIdx.x;
  int swz = (bid & 7) * (nwg / 8) + (bid >> 3);
  size_t m0 = (size_t)(swz / 16) * 256, n0 = (size_t)(swz % 16) * 256;
  floatx4 acc[8][4] = {};
  kloop8<1024, 1024, 16>(A, B, m0, n0, smem, acc);

  const int t = threadIdx.x;
  const int wid = t >> 6, lane = t & 63, wm = wid >> 2, wn = wid & 3, lr = lane & 15, kg = lane >> 4;
  float* sE = (float*)smem;  // [32][256]
  const int erow = t >> 4, ec0 = (t & 15) * 16;
#pragma unroll
  for (int mi = 0; mi < 8; ++mi) {
#pragma unroll
    for (int ni = 0; ni < 4; ++ni)
#pragma unroll
      for (int r = 0; r < 4; ++r)
        sE[(wm * 16 + kg * 4 + r) * 256 + wn * 64 + ni * 16 + lr] = acc[mi][ni][r];
    __syncthreads();
    const size_t gm = m0 + (size_t)(erow >> 4) * 128 + mi * 16 + (erow & 15);
    const int gc = (int)n0 + ec0;
    alignas(16) unsigned short pk[16];
#pragma unroll
    for (int i = 0; i < 16; ++i) {
      float v = sE[erow * 256 + ec0 + i] + bias[gc + i];
      float g = 0.5f * v * (1.0f + erff(v * 0.70710678118654752440f));
      pk[i] = f2bf(g);
    }
    *(ushortx8*)(H + gm * 4096 + gc) = *(const ushortx8*)&pk[0];
    *(ushortx8*)(H + gm * 4096 + gc + 8) = *(const ushortx8*)&pk[8];
    __syncthreads();
  }
}

// ------------- GEMM2: OUT = H @ W2T^T + b2 + lora, f32 out. M=16384 N=1024 K=4096 -------------
__global__ __launch_bounds__(512, 2) void gemm2_8ph(const unsigned short* __restrict__ A,
                                                    const unsigned short* __restrict__ B,
                                                    const float* __restrict__ bias,
                                                    const float* __restrict__ lmid,
                                                    const float* __restrict__ a_up,
                                                    const int* __restrict__ idxp,
                                                    float* __restrict__ OUT) {
  extern __shared__ char smem[];
  const int nwg = 256;
  int bid = blockIdx.x;
  int swz = (bid & 7) * (nwg / 8) + (bid >> 3);
  size_t m0 = (size_t)(swz / 4) * 256, n0 = (size_t)(swz % 4) * 256;
  floatx4 acc[8][4] = {};
  kloop8<4096, 4096, 64>(A, B, m0, n0, smem, acc);

  const int t = threadIdx.x;
  const int wid = t >> 6, lane = t & 63, wm = wid >> 2, wn = wid & 3, lr = lane & 15, kg = lane >> 4;
  float* sE = (float*)smem;  // [32][256]
  const float* aup = a_up + (size_t)(*idxp) * 8192;
  const int erow = t >> 4, ec0 = (t & 15) * 16;
#pragma unroll
  for (int mi = 0; mi < 8; ++mi) {
#pragma unroll
    for (int ni = 0; ni < 4; ++ni)
#pragma unroll
      for (int r = 0; r < 4; ++r)
        sE[(wm * 16 + kg * 4 + r) * 256 + wn * 64 + ni * 16 + lr] = acc[mi][ni][r];
    __syncthreads();
    const size_t gm = m0 + (size_t)(erow >> 4) * 128 + mi * 16 + (erow & 15);
    const int gc = (int)n0 + ec0;
    alignas(16) float lmv[8];
    *(float4*)&lmv[0] = *(const float4*)(lmid + gm * 8);
    *(float4*)&lmv[4] = *(const float4*)(lmid + gm * 8 + 4);
    alignas(16) float v[16];
#pragma unroll
    for (int i = 0; i < 16; ++i) v[i] = sE[erow * 256 + ec0 + i] + bias[gc + i];
#pragma unroll
    for (int r = 0; r < 8; ++r) {
      const float lw = lmv[r];
      const float* ar = aup + r * 1024 + gc;
#pragma unroll
      for (int i = 0; i < 16; ++i) v[i] += lw * ar[i];
    }
#pragma unroll
    for (int i = 0; i < 16; i += 4)
      *(float4*)(OUT + gm * 1024 + gc + i) = *(const float4*)&v[i];
    __syncthreads();
  }
}

extern "C" void kernel_launch(void* const* d_in, const int* in_sizes, int n_in,
                              void* d_out, int out_size, void* d_ws, size_t ws_size,
                              hipStream_t stream) {
  const float* x      = (const float*)d_in[0];
  const float* w1     = (const float*)d_in[1];
  const float* b1     = (const float*)d_in[2];
  const float* w2     = (const float*)d_in[3];
  const float* b2     = (const float*)d_in[4];
  const float* a_down = (const float*)d_in[5];
  const float* a_up   = (const float*)d_in[6];
  const int*   idx    = (const int*)d_in[7];
  float* out = (float*)d_out;

  char* ws = (char*)d_ws;
  unsigned short* Xb  = (unsigned short*)(ws);              // 16384x1024 bf16 = 32 MiB
  unsigned short* W1T = (unsigned short*)(ws + 33554432);   // 4096x1024 bf16 = 8 MiB
  unsigned short* W2T = (unsigned short*)(ws + 41943040);   // 1024x4096 bf16 = 8 MiB
  float*          LMID = (float*)(ws + 50331648);           // 16384x8 f32 = 0.5 MiB
  unsigned short* H   = (unsigned short*)(ws + 50855936);   // 16384x4096 bf16 = 128 MiB

  (void)hipFuncSetAttribute((const void*)gemm1_8ph, hipFuncAttributeMaxDynamicSharedMemorySize, 131072);
  (void)hipFuncSetAttribute((const void*)gemm2_8ph, hipFuncAttributeMaxDynamicSharedMemorySize, 131072);

  convert_x_kernel<<<16384, 256, 0, stream>>>((const float4*)x, (ushort4*)Xb);
  transpose_bf16_kernel<<<dim3(128, 32), dim3(32, 8), 0, stream>>>(w1, W1T, 1024, 4096);
  transpose_bf16_kernel<<<dim3(32, 128), dim3(32, 8), 0, stream>>>(w2, W2T, 4096, 1024);
  lora_mid_kernel<<<4096, 256, 0, stream>>>(x, a_down, idx, LMID);
  gemm1_8ph<<<1024, 512, 131072, stream>>>(Xb, W1T, b1, H);
  gemm2_8ph<<<256, 512, 131072, stream>>>(H, W2T, b2, LMID, a_up, idx, out);
}

// Round 7
// 688.195 us; speedup vs baseline: 1.4611x; 1.4611x over previous
//
#include <hip/hip_runtime.h>
#include <hip/hip_bf16.h>
#include <math.h>

typedef __attribute__((ext_vector_type(4))) float floatx4;
typedef __attribute__((ext_vector_type(8))) __bf16 bfloatx8;
typedef __attribute__((ext_vector_type(8))) unsigned short ushortx8;

static __device__ __forceinline__ unsigned short f2bf(float f) {
  __hip_bfloat16 h = __float2bfloat16(f);
  return *reinterpret_cast<unsigned short*>(&h);
}

static __device__ __forceinline__ void gload16(const void* g, void* l) {
  __builtin_amdgcn_global_load_lds(
      (const __attribute__((address_space(1))) unsigned int*)g,
      (__attribute__((address_space(3))) unsigned int*)l, 16, 0, 0);
}

// ---------------- x: f32 -> bf16 ----------------
__global__ __launch_bounds__(256) void convert_x_kernel(const float4* __restrict__ in,
                                                        ushort4* __restrict__ out) {
  int i = blockIdx.x * 256 + threadIdx.x;
  float4 v = in[i];
  ushort4 o;
  o.x = f2bf(v.x); o.y = f2bf(v.y); o.z = f2bf(v.z); o.w = f2bf(v.w);
  out[i] = o;
}

// ------------- transpose + cast: out[c][r] = bf16(in[r][c]) -------------
__global__ __launch_bounds__(256) void transpose_bf16_kernel(const float* __restrict__ in,
                                                             unsigned short* __restrict__ out,
                                                             int rows, int cols) {
  __shared__ float tile[32][33];
  int c0 = blockIdx.x * 32, r0 = blockIdx.y * 32;
  int tx = threadIdx.x, ty = threadIdx.y;
#pragma unroll
  for (int j = 0; j < 32; j += 8)
    tile[ty + j][tx] = in[(size_t)(r0 + ty + j) * cols + c0 + tx];
  __syncthreads();
#pragma unroll
  for (int j = 0; j < 32; j += 8)
    out[(size_t)(c0 + ty + j) * rows + r0 + tx] = f2bf(tile[tx][ty + j]);
}

// ------------- lora_mid[m][r] = sum_k x[m][k] * a_down[idx][k][r] -------------
__global__ __launch_bounds__(256) void lora_mid_kernel(const float* __restrict__ x,
                                                       const float* __restrict__ a_down,
                                                       const int* __restrict__ idxp,
                                                       float* __restrict__ lmid) {
  __shared__ float ad[1024 * 9];
  const float* A = a_down + (size_t)(*idxp) * (1024 * 8);
  int t = threadIdx.x;
  for (int i = t; i < 8192; i += 256) ad[(i >> 3) * 9 + (i & 7)] = A[i];
  __syncthreads();
  int wid = t >> 6, lane = t & 63;
  int row = blockIdx.x * 4 + wid;
  const float* xr = x + (size_t)row * 1024;
  float acc[8] = {0.f, 0.f, 0.f, 0.f, 0.f, 0.f, 0.f, 0.f};
  for (int i = 0; i < 16; ++i) {
    int k = i * 64 + lane;
    float xv = xr[k];
#pragma unroll
    for (int r = 0; r < 8; ++r) acc[r] += xv * ad[k * 9 + r];
  }
#pragma unroll
  for (int off = 32; off > 0; off >>= 1) {
#pragma unroll
    for (int r = 0; r < 8; ++r) acc[r] += __shfl_xor(acc[r], off);
  }
  if (lane == 0) {
    *(float4*)(lmid + (size_t)row * 8) = make_float4(acc[0], acc[1], acc[2], acc[3]);
    *(float4*)(lmid + (size_t)row * 8 + 4) = make_float4(acc[4], acc[5], acc[6], acc[7]);
  }
}

// ===== R2-proven 128x128 GEMM structure (BK=32, 4 waves, 16 KiB LDS), plus:
//  (a) LDS bank swizzle: logical col-block cb stored at physical cb ^ ((row>>1)&3).
//      Staging (linear gload_lds dest) pre-swizzles the GLOBAL source column:
//      scol = ((t&3) ^ ((t>>3)&3))*8; reads use kgx = kg ^ ((lr>>1)&3) (zero-cost fold).
//      Verified conflict-free: quarter-wave quads = (lr&1)*4 + (kg^((lr>>1)&3)) -> 2 lanes/quad.
//  (b) XCD-square block mapping (see kernel bodies): co-resident blocks on an XCD form an
//      8x8 m-x-n square -> A/B panels L2-deduped, vmcnt(0) drains hit L2 not cold HBM.

// ------------- GEMM1: H[m][f] = gelu( Xb . W1T^T + b1 ), bf16 out. grid 4096 -------------
__global__ __launch_bounds__(256) void gemm1_gelu_kernel(const unsigned short* __restrict__ A,
                                                         const unsigned short* __restrict__ B,
                                                         const float* __restrict__ bias,
                                                         unsigned short* __restrict__ H) {
  __shared__ __align__(16) char smem[16384];
  unsigned short* As = (unsigned short*)smem;           // [128][32] swizzled
  unsigned short* Bs = (unsigned short*)(smem + 8192);  // [128][32] swizzled
  const int t = threadIdx.x;
  const int wid = t >> 6, lane = t & 63;
  const int wr = wid >> 1, wc = wid & 1;
  const int lr = lane & 15, kg = lane >> 4;
  const int kgx = kg ^ ((lr >> 1) & 3);  // swizzled col-block for LDS reads

  // XCD-square mapping: grid = 128(m) x 32(n); per XCD 8 squares of 8x8
  const int bid = blockIdx.x;
  const int xcd = bid & 7, j = bid >> 3;       // j 0..511
  const int sq = j >> 6, i = j & 63;           // sq 0..7
  const int mt = xcd * 16 + (sq & 1) * 8 + (i & 7);
  const int nt = (sq >> 1) * 8 + (i >> 3);
  const size_t m0 = (size_t)mt * 128;
  const size_t n0 = (size_t)nt * 128;

  const int srow = t >> 2, scol = ((t & 3) ^ ((t >> 3) & 3)) * 8;  // pre-swizzled source col
  const unsigned short* gA0 = A + (m0 + srow) * 1024 + scol;
  const unsigned short* gA1 = A + (m0 + 64 + srow) * 1024 + scol;
  const unsigned short* gB0 = B + (n0 + srow) * 1024 + scol;
  const unsigned short* gB1 = B + (n0 + 64 + srow) * 1024 + scol;
  char* lA = smem + (wid << 10);
  char* lB = smem + 8192 + (wid << 10);

  floatx4 acc[4][4] = {};
#pragma unroll 1
  for (int kt = 0; kt < 32; ++kt) {
    const int ko = kt * 32;
    __syncthreads();
    gload16(gA0 + ko, lA);
    gload16(gA1 + ko, lA + 4096);
    gload16(gB0 + ko, lB);
    gload16(gB1 + ko, lB + 4096);
    __syncthreads();
    bfloatx8 af[4], bfv[4];
#pragma unroll
    for (int mi = 0; mi < 4; ++mi)
      af[mi] = *(const bfloatx8*)(As + (wr * 64 + mi * 16 + lr) * 32 + kgx * 8);
#pragma unroll
    for (int ni = 0; ni < 4; ++ni)
      bfv[ni] = *(const bfloatx8*)(Bs + (wc * 64 + ni * 16 + lr) * 32 + kgx * 8);
#pragma unroll
    for (int mi = 0; mi < 4; ++mi) {
#pragma unroll
      for (int ni = 0; ni < 4; ++ni)
        acc[mi][ni] = __builtin_amdgcn_mfma_f32_16x16x32_bf16(af[mi], bfv[ni], acc[mi][ni], 0, 0, 0);
    }
  }

  // epilogue (fully unrolled, rule #20): LDS transpose -> coalesced bf16 stores
  __syncthreads();
  float* sE = (float*)smem;  // 4096 f32
  const int row32 = t >> 3, col0 = (t & 7) * 16;
  const int stripe = row32 >> 4, lrow = row32 & 15;
#pragma unroll
  for (int mi = 0; mi < 4; ++mi) {
#pragma unroll
    for (int ni = 0; ni < 4; ++ni) {
#pragma unroll
      for (int r = 0; r < 4; ++r)
        sE[wr * 2048 + (kg * 4 + r) * 128 + wc * 64 + ni * 16 + lr] = acc[mi][ni][r];
    }
    __syncthreads();
    const size_t gm = m0 + stripe * 64 + mi * 16 + lrow;
    const float* src = sE + stripe * 2048 + lrow * 128 + col0;
    alignas(16) unsigned short pk[16];
#pragma unroll
    for (int i2 = 0; i2 < 16; ++i2) {
      float v = src[i2] + bias[n0 + col0 + i2];
      float g = 0.5f * v * (1.0f + erff(v * 0.70710678118654752440f));
      pk[i2] = f2bf(g);
    }
    *(ushortx8*)(H + gm * 4096 + n0 + col0) = *(const ushortx8*)&pk[0];
    *(ushortx8*)(H + gm * 4096 + n0 + col0 + 8) = *(const ushortx8*)&pk[8];
    __syncthreads();
  }
}

// ------------- GEMM2: OUT[m][d] = H . W2T^T + b2 + lora, f32 out. grid 1024 -------------
__global__ __launch_bounds__(256) void gemm2_out_kernel(const unsigned short* __restrict__ A,
                                                        const unsigned short* __restrict__ B,
                                                        const float* __restrict__ bias,
                                                        const float* __restrict__ lmid,
                                                        const float* __restrict__ a_up,
                                                        const int* __restrict__ idxp,
                                                        float* __restrict__ OUT) {
  __shared__ __align__(16) char smem[16384];
  unsigned short* As = (unsigned short*)smem;
  unsigned short* Bs = (unsigned short*)(smem + 8192);
  const int t = threadIdx.x;
  const int wid = t >> 6, lane = t & 63;
  const int wr = wid >> 1, wc = wid & 1;
  const int lr = lane & 15, kg = lane >> 4;
  const int kgx = kg ^ ((lr >> 1) & 3);

  // XCD-square mapping: grid = 128(m) x 8(n); per XCD 2 squares of 8x8
  const int bid = blockIdx.x;
  const int xcd = bid & 7, j = bid >> 3;   // j 0..127
  const int sq = j >> 6, i = j & 63;       // sq 0..1
  const int mt = xcd * 16 + sq * 8 + (i & 7);
  const int nt = i >> 3;
  const size_t m0 = (size_t)mt * 128;
  const size_t n0 = (size_t)nt * 128;

  const int srow = t >> 2, scol = ((t & 3) ^ ((t >> 3) & 3)) * 8;
  const unsigned short* gA0 = A + (m0 + srow) * 4096 + scol;
  const unsigned short* gA1 = A + (m0 + 64 + srow) * 4096 + scol;
  const unsigned short* gB0 = B + (n0 + srow) * 4096 + scol;
  const unsigned short* gB1 = B + (n0 + 64 + srow) * 4096 + scol;
  char* lA = smem + (wid << 10);
  char* lB = smem + 8192 + (wid << 10);

  floatx4 acc[4][4] = {};
#pragma unroll 1
  for (int kt = 0; kt < 128; ++kt) {
    const int ko = kt * 32;
    __syncthreads();
    gload16(gA0 + ko, lA);
    gload16(gA1 + ko, lA + 4096);
    gload16(gB0 + ko, lB);
    gload16(gB1 + ko, lB + 4096);
    __syncthreads();
    bfloatx8 af[4], bfv[4];
#pragma unroll
    for (int mi = 0; mi < 4; ++mi)
      af[mi] = *(const bfloatx8*)(As + (wr * 64 + mi * 16 + lr) * 32 + kgx * 8);
#pragma unroll
    for (int ni = 0; ni < 4; ++ni)
      bfv[ni] = *(const bfloatx8*)(Bs + (wc * 64 + ni * 16 + lr) * 32 + kgx * 8);
#pragma unroll
    for (int mi = 0; mi < 4; ++mi) {
#pragma unroll
      for (int ni = 0; ni < 4; ++ni)
        acc[mi][ni] = __builtin_amdgcn_mfma_f32_16x16x32_bf16(af[mi], bfv[ni], acc[mi][ni], 0, 0, 0);
    }
  }

  // epilogue (fully unrolled): LDS transpose -> coalesced f32 stores + bias + LoRA
  __syncthreads();
  float* sE = (float*)smem;
  const float* aup = a_up + (size_t)(*idxp) * 8192;
  const int row32 = t >> 3, col0 = (t & 7) * 16;
  const int stripe = row32 >> 4, lrow = row32 & 15;
#pragma unroll
  for (int mi = 0; mi < 4; ++mi) {
#pragma unroll
    for (int ni = 0; ni < 4; ++ni) {
#pragma unroll
      for (int r = 0; r < 4; ++r)
        sE[wr * 2048 + (kg * 4 + r) * 128 + wc * 64 + ni * 16 + lr] = acc[mi][ni][r];
    }
    __syncthreads();
    const size_t gm = m0 + stripe * 64 + mi * 16 + lrow;
    const float* src = sE + stripe * 2048 + lrow * 128 + col0;
    alignas(16) float lmv[8];
    *(float4*)&lmv[0] = *(const float4*)(lmid + gm * 8);
    *(float4*)&lmv[4] = *(const float4*)(lmid + gm * 8 + 4);
    alignas(16) float v[16];
#pragma unroll
    for (int i2 = 0; i2 < 16; ++i2) v[i2] = src[i2] + bias[n0 + col0 + i2];
#pragma unroll
    for (int r = 0; r < 8; ++r) {
      const float lw = lmv[r];
      const float* ar = aup + r * 1024 + n0 + col0;
#pragma unroll
      for (int i2 = 0; i2 < 16; ++i2) v[i2] += lw * ar[i2];
    }
#pragma unroll
    for (int i2 = 0; i2 < 16; i2 += 4)
      *(float4*)(OUT + gm * 1024 + n0 + col0 + i2) = *(const float4*)&v[i2];
    __syncthreads();
  }
}

extern "C" void kernel_launch(void* const* d_in, const int* in_sizes, int n_in,
                              void* d_out, int out_size, void* d_ws, size_t ws_size,
                              hipStream_t stream) {
  const float* x      = (const float*)d_in[0];
  const float* w1     = (const float*)d_in[1];
  const float* b1     = (const float*)d_in[2];
  const float* w2     = (const float*)d_in[3];
  const float* b2     = (const float*)d_in[4];
  const float* a_down = (const float*)d_in[5];
  const float* a_up   = (const float*)d_in[6];
  const int*   idx    = (const int*)d_in[7];
  float* out = (float*)d_out;

  char* ws = (char*)d_ws;
  unsigned short* Xb  = (unsigned short*)(ws);              // 16384x1024 bf16 = 32 MiB
  unsigned short* W1T = (unsigned short*)(ws + 33554432);   // 4096x1024 bf16 = 8 MiB
  unsigned short* W2T = (unsigned short*)(ws + 41943040);   // 1024x4096 bf16 = 8 MiB
  float*          LMID = (float*)(ws + 50331648);           // 16384x8 f32 = 0.5 MiB
  unsigned short* H   = (unsigned short*)(ws + 50855936);   // 16384x4096 bf16 = 128 MiB

  convert_x_kernel<<<16384, 256, 0, stream>>>((const float4*)x, (ushort4*)Xb);
  transpose_bf16_kernel<<<dim3(128, 32), dim3(32, 8), 0, stream>>>(w1, W1T, 1024, 4096);
  transpose_bf16_kernel<<<dim3(32, 128), dim3(32, 8), 0, stream>>>(w2, W2T, 4096, 1024);
  lora_mid_kernel<<<4096, 256, 0, stream>>>(x, a_down, idx, LMID);
  gemm1_gelu_kernel<<<4096, 256, 0, stream>>>(Xb, W1T, b1, H);
  gemm2_out_kernel<<<1024, 256, 0, stream>>>(H, W2T, b2, LMID, a_up, idx, out);
}

// Round 8
// 567.897 us; speedup vs baseline: 1.7706x; 1.2118x over previous
//
#include <hip/hip_runtime.h>
#include <hip/hip_bf16.h>
#include <math.h>

typedef __attribute__((ext_vector_type(4))) float floatx4;
typedef __attribute__((ext_vector_type(8))) __bf16 bfloatx8;
typedef __attribute__((ext_vector_type(8))) unsigned short ushortx8;

static __device__ __forceinline__ unsigned short f2bf(float f) {
  __hip_bfloat16 h = __float2bfloat16(f);
  return *reinterpret_cast<unsigned short*>(&h);
}

static __device__ __forceinline__ void gload16(const void* g, void* l) {
  __builtin_amdgcn_global_load_lds(
      (const __attribute__((address_space(1))) unsigned int*)g,
      (__attribute__((address_space(3))) unsigned int*)l, 16, 0, 0);
}

#define S_BARRIER() __builtin_amdgcn_s_barrier()
#define WAIT_VM0() do { asm volatile("s_waitcnt vmcnt(0)" ::: "memory"); __builtin_amdgcn_sched_barrier(0); } while (0)

// ---------------- x: f32 -> bf16 ----------------
__global__ __launch_bounds__(256) void convert_x_kernel(const float4* __restrict__ in,
                                                        ushort4* __restrict__ out) {
  int i = blockIdx.x * 256 + threadIdx.x;
  float4 v = in[i];
  ushort4 o;
  o.x = f2bf(v.x); o.y = f2bf(v.y); o.z = f2bf(v.z); o.w = f2bf(v.w);
  out[i] = o;
}

// ------------- transpose + cast: out[c][r] = bf16(in[r][c]) -------------
__global__ __launch_bounds__(256) void transpose_bf16_kernel(const float* __restrict__ in,
                                                             unsigned short* __restrict__ out,
                                                             int rows, int cols) {
  __shared__ float tile[32][33];
  int c0 = blockIdx.x * 32, r0 = blockIdx.y * 32;
  int tx = threadIdx.x, ty = threadIdx.y;
#pragma unroll
  for (int j = 0; j < 32; j += 8)
    tile[ty + j][tx] = in[(size_t)(r0 + ty + j) * cols + c0 + tx];
  __syncthreads();
#pragma unroll
  for (int j = 0; j < 32; j += 8)
    out[(size_t)(c0 + ty + j) * rows + r0 + tx] = f2bf(tile[tx][ty + j]);
}

// ------------- lora_mid[m][r] = sum_k x[m][k] * a_down[idx][k][r] -------------
__global__ __launch_bounds__(256) void lora_mid_kernel(const float* __restrict__ x,
                                                       const float* __restrict__ a_down,
                                                       const int* __restrict__ idxp,
                                                       float* __restrict__ lmid) {
  __shared__ float ad[1024 * 9];
  const float* A = a_down + (size_t)(*idxp) * (1024 * 8);
  int t = threadIdx.x;
  for (int i = t; i < 8192; i += 256) ad[(i >> 3) * 9 + (i & 7)] = A[i];
  __syncthreads();
  int wid = t >> 6, lane = t & 63;
  int row = blockIdx.x * 4 + wid;
  const float* xr = x + (size_t)row * 1024;
  float acc[8] = {0.f, 0.f, 0.f, 0.f, 0.f, 0.f, 0.f, 0.f};
  for (int i = 0; i < 16; ++i) {
    int k = i * 64 + lane;
    float xv = xr[k];
#pragma unroll
    for (int r = 0; r < 8; ++r) acc[r] += xv * ad[k * 9 + r];
  }
#pragma unroll
  for (int off = 32; off > 0; off >>= 1) {
#pragma unroll
    for (int r = 0; r < 8; ++r) acc[r] += __shfl_xor(acc[r], off);
  }
  if (lane == 0) {
    *(float4*)(lmid + (size_t)row * 8) = make_float4(acc[0], acc[1], acc[2], acc[3]);
    *(float4*)(lmid + (size_t)row * 8 + 4) = make_float4(acc[4], acc[5], acc[6], acc[7]);
  }
}

// ===== 128x128 GEMM (BK=32, 4 waves) + T3 minimum 2-phase ping-pong (32 KiB LDS dbuf):
//   per K-step: STAGE(buf^1, kt+1)  ->  ds_read frags(buf) -> 16 MFMA -> vmcnt(0) -> s_barrier
//   STAGE targets the buffer whose readers all finished before the PREVIOUS barrier
//   (race-free by construction); the drain comes after the whole compute phase is issued,
//   so the staged loads have ~300+ cyc in flight before vmcnt(0) (vs 0 in the 1-phase R7).
//   LDS swizzle (proven R7): physical col-block = logical ^ ((row>>1)&3); staging pre-swizzles
//   the GLOBAL source col (scol), reads fold kgx = kg ^ ((lr>>1)&3). XCD-square mapping kept.
template <int LD, int NKT>
static __device__ __forceinline__ void gemm_kloop2ph(const unsigned short* __restrict__ A,
                                                     const unsigned short* __restrict__ B,
                                                     size_t m0, size_t n0, char* smem,
                                                     floatx4 (&acc)[4][4]) {
  const int t = threadIdx.x;
  const int wid = t >> 6, lane = t & 63;
  const int wr = wid >> 1, wc = wid & 1;
  const int lr = lane & 15, kg = lane >> 4;
  const int kgx = kg ^ ((lr >> 1) & 3);
  const int srow = t >> 2, scol = ((t & 3) ^ ((t >> 3) & 3)) * 8;
  const unsigned short* gA0 = A + (m0 + srow) * LD + scol;
  const unsigned short* gA1 = A + (m0 + 64 + srow) * LD + scol;
  const unsigned short* gB0 = B + (n0 + srow) * LD + scol;
  const unsigned short* gB1 = B + (n0 + 64 + srow) * LD + scol;
  const unsigned ldsOff = (unsigned)(wid << 10);

#define STAGE(bufb, ko)                           \
  do {                                            \
    char* lA_ = smem + (bufb) + ldsOff;           \
    char* lB_ = smem + (bufb) + 8192 + ldsOff;    \
    gload16(gA0 + (ko), lA_);                     \
    gload16(gA1 + (ko), lA_ + 4096);              \
    gload16(gB0 + (ko), lB_);                     \
    gload16(gB1 + (ko), lB_ + 4096);              \
  } while (0)

  // prologue: stage tile 0 into buf0
  STAGE(0u, 0);
  WAIT_VM0();
  S_BARRIER();

#pragma unroll 1
  for (int kt = 0; kt < NKT; ++kt) {
    const unsigned cur = (unsigned)(kt & 1) << 14;
    const unsigned nxt = cur ^ 16384u;
    if (kt + 1 < NKT) STAGE(nxt, (kt + 1) * 32);  // issue BEFORE compute (T3)
    const unsigned short* As = (const unsigned short*)(smem + cur);
    const unsigned short* Bs = (const unsigned short*)(smem + cur + 8192);
    bfloatx8 af[4], bfv[4];
#pragma unroll
    for (int mi = 0; mi < 4; ++mi)
      af[mi] = *(const bfloatx8*)(As + (wr * 64 + mi * 16 + lr) * 32 + kgx * 8);
#pragma unroll
    for (int ni = 0; ni < 4; ++ni)
      bfv[ni] = *(const bfloatx8*)(Bs + (wc * 64 + ni * 16 + lr) * 32 + kgx * 8);
#pragma unroll
    for (int mi = 0; mi < 4; ++mi) {
#pragma unroll
      for (int ni = 0; ni < 4; ++ni)
        acc[mi][ni] = __builtin_amdgcn_mfma_f32_16x16x32_bf16(af[mi], bfv[ni], acc[mi][ni], 0, 0, 0);
    }
    WAIT_VM0();   // next tile fully landed (issued one full compute-phase ago)
    S_BARRIER();  // all waves done reading cur + staging complete -> safe swap
  }
#undef STAGE
}

// ------------- GEMM1: H[m][f] = gelu( Xb . W1T^T + b1 ), bf16 out. grid 4096 -------------
__global__ __launch_bounds__(256) void gemm1_gelu_kernel(const unsigned short* __restrict__ A,
                                                         const unsigned short* __restrict__ B,
                                                         const float* __restrict__ bias,
                                                         unsigned short* __restrict__ H) {
  __shared__ __align__(16) char smem[32768];
  const int t = threadIdx.x;
  const int wid = t >> 6, lane = t & 63;
  const int wr = wid >> 1, wc = wid & 1;
  const int lr = lane & 15, kg = lane >> 4;

  // XCD-square mapping: grid = 128(m) x 32(n); per XCD 8 squares of 8x8
  const int bid = blockIdx.x;
  const int xcd = bid & 7, j = bid >> 3;       // j 0..511
  const int sq = j >> 6, i = j & 63;           // sq 0..7
  const int mt = xcd * 16 + (sq & 1) * 8 + (i & 7);
  const int nt = (sq >> 1) * 8 + (i >> 3);
  const size_t m0 = (size_t)mt * 128;
  const size_t n0 = (size_t)nt * 128;

  floatx4 acc[4][4] = {};
  gemm_kloop2ph<1024, 32>(A, B, m0, n0, smem, acc);

  // epilogue (fully unrolled, rule #20): LDS transpose -> coalesced bf16 stores
  __syncthreads();
  float* sE = (float*)smem;  // 4096 f32
  const int row32 = t >> 3, col0 = (t & 7) * 16;
  const int stripe = row32 >> 4, lrow = row32 & 15;
#pragma unroll
  for (int mi = 0; mi < 4; ++mi) {
#pragma unroll
    for (int ni = 0; ni < 4; ++ni) {
#pragma unroll
      for (int r = 0; r < 4; ++r)
        sE[wr * 2048 + (kg * 4 + r) * 128 + wc * 64 + ni * 16 + lr] = acc[mi][ni][r];
    }
    __syncthreads();
    const size_t gm = m0 + stripe * 64 + mi * 16 + lrow;
    const float* src = sE + stripe * 2048 + lrow * 128 + col0;
    alignas(16) unsigned short pk[16];
#pragma unroll
    for (int i2 = 0; i2 < 16; ++i2) {
      float v = src[i2] + bias[n0 + col0 + i2];
      float g = 0.5f * v * (1.0f + erff(v * 0.70710678118654752440f));
      pk[i2] = f2bf(g);
    }
    *(ushortx8*)(H + gm * 4096 + n0 + col0) = *(const ushortx8*)&pk[0];
    *(ushortx8*)(H + gm * 4096 + n0 + col0 + 8) = *(const ushortx8*)&pk[8];
    __syncthreads();
  }
}

// ------------- GEMM2: OUT[m][d] = H . W2T^T + b2 + lora, f32 out. grid 1024 -------------
__global__ __launch_bounds__(256) void gemm2_out_kernel(const unsigned short* __restrict__ A,
                                                        const unsigned short* __restrict__ B,
                                                        const float* __restrict__ bias,
                                                        const float* __restrict__ lmid,
                                                        const float* __restrict__ a_up,
                                                        const int* __restrict__ idxp,
                                                        float* __restrict__ OUT) {
  __shared__ __align__(16) char smem[32768];
  const int t = threadIdx.x;
  const int wid = t >> 6, lane = t & 63;
  const int wr = wid >> 1, wc = wid & 1;
  const int lr = lane & 15, kg = lane >> 4;

  // XCD-square mapping: grid = 128(m) x 8(n); per XCD 2 squares of 8x8
  const int bid = blockIdx.x;
  const int xcd = bid & 7, j = bid >> 3;   // j 0..127
  const int sq = j >> 6, i = j & 63;       // sq 0..1
  const int mt = xcd * 16 + sq * 8 + (i & 7);
  const int nt = i >> 3;
  const size_t m0 = (size_t)mt * 128;
  const size_t n0 = (size_t)nt * 128;

  floatx4 acc[4][4] = {};
  gemm_kloop2ph<4096, 128>(A, B, m0, n0, smem, acc);

  // epilogue (fully unrolled): LDS transpose -> coalesced f32 stores + bias + LoRA
  __syncthreads();
  float* sE = (float*)smem;
  const float* aup = a_up + (size_t)(*idxp) * 8192;
  const int row32 = t >> 3, col0 = (t & 7) * 16;
  const int stripe = row32 >> 4, lrow = row32 & 15;
#pragma unroll
  for (int mi = 0; mi < 4; ++mi) {
#pragma unroll
    for (int ni = 0; ni < 4; ++ni) {
#pragma unroll
      for (int r = 0; r < 4; ++r)
        sE[wr * 2048 + (kg * 4 + r) * 128 + wc * 64 + ni * 16 + lr] = acc[mi][ni][r];
    }
    __syncthreads();
    const size_t gm = m0 + stripe * 64 + mi * 16 + lrow;
    const float* src = sE + stripe * 2048 + lrow * 128 + col0;
    alignas(16) float lmv[8];
    *(float4*)&lmv[0] = *(const float4*)(lmid + gm * 8);
    *(float4*)&lmv[4] = *(const float4*)(lmid + gm * 8 + 4);
    alignas(16) float v[16];
#pragma unroll
    for (int i2 = 0; i2 < 16; ++i2) v[i2] = src[i2] + bias[n0 + col0 + i2];
#pragma unroll
    for (int r = 0; r < 8; ++r) {
      const float lw = lmv[r];
      const float* ar = aup + r * 1024 + n0 + col0;
#pragma unroll
      for (int i2 = 0; i2 < 16; ++i2) v[i2] += lw * ar[i2];
    }
#pragma unroll
    for (int i2 = 0; i2 < 16; i2 += 4)
      *(float4*)(OUT + gm * 1024 + n0 + col0 + i2) = *(const float4*)&v[i2];
    __syncthreads();
  }
}

extern "C" void kernel_launch(void* const* d_in, const int* in_sizes, int n_in,
                              void* d_out, int out_size, void* d_ws, size_t ws_size,
                              hipStream_t stream) {
  const float* x      = (const float*)d_in[0];
  const float* w1     = (const float*)d_in[1];
  const float* b1     = (const float*)d_in[2];
  const float* w2     = (const float*)d_in[3];
  const float* b2     = (const float*)d_in[4];
  const float* a_down = (const float*)d_in[5];
  const float* a_up   = (const float*)d_in[6];
  const int*   idx    = (const int*)d_in[7];
  float* out = (float*)d_out;

  char* ws = (char*)d_ws;
  unsigned short* Xb  = (unsigned short*)(ws);              // 16384x1024 bf16 = 32 MiB
  unsigned short* W1T = (unsigned short*)(ws + 33554432);   // 4096x1024 bf16 = 8 MiB
  unsigned short* W2T = (unsigned short*)(ws + 41943040);   // 1024x4096 bf16 = 8 MiB
  float*          LMID = (float*)(ws + 50331648);           // 16384x8 f32 = 0.5 MiB
  unsigned short* H   = (unsigned short*)(ws + 50855936);   // 16384x4096 bf16 = 128 MiB

  convert_x_kernel<<<16384, 256, 0, stream>>>((const float4*)x, (ushort4*)Xb);
  transpose_bf16_kernel<<<dim3(128, 32), dim3(32, 8), 0, stream>>>(w1, W1T, 1024, 4096);
  transpose_bf16_kernel<<<dim3(32, 128), dim3(32, 8), 0, stream>>>(w2, W2T, 4096, 1024);
  lora_mid_kernel<<<4096, 256, 0, stream>>>(x, a_down, idx, LMID);
  gemm1_gelu_kernel<<<4096, 256, 0, stream>>>(Xb, W1T, b1, H);
  gemm2_out_kernel<<<1024, 256, 0, stream>>>(H, W2T, b2, LMID, a_up, idx, out);
}

// Round 9
// 519.693 us; speedup vs baseline: 1.9349x; 1.0928x over previous
//
#include <hip/hip_runtime.h>
#include <hip/hip_bf16.h>
#include <math.h>

typedef __attribute__((ext_vector_type(4))) float floatx4;
typedef __attribute__((ext_vector_type(8))) __bf16 bfloatx8;
typedef __attribute__((ext_vector_type(8))) unsigned short ushortx8;

static __device__ __forceinline__ unsigned short f2bf(float f) {
  __hip_bfloat16 h = __float2bfloat16(f);
  return *reinterpret_cast<unsigned short*>(&h);
}

static __device__ __forceinline__ void gload16(const void* g, void* l) {
  __builtin_amdgcn_global_load_lds(
      (const __attribute__((address_space(1))) unsigned int*)g,
      (__attribute__((address_space(3))) unsigned int*)l, 16, 0, 0);
}

#define S_BARRIER() __builtin_amdgcn_s_barrier()
#define WAIT_VM(n)  do { asm volatile("s_waitcnt vmcnt(" #n ")" ::: "memory"); __builtin_amdgcn_sched_barrier(0); } while (0)

// ------------- transpose + cast: out[c][r] = bf16(in[r][c]) -------------
__global__ __launch_bounds__(256) void transpose_bf16_kernel(const float* __restrict__ in,
                                                             unsigned short* __restrict__ out,
                                                             int rows, int cols) {
  __shared__ float tile[32][33];
  int c0 = blockIdx.x * 32, r0 = blockIdx.y * 32;
  int tx = threadIdx.x, ty = threadIdx.y;
#pragma unroll
  for (int j = 0; j < 32; j += 8)
    tile[ty + j][tx] = in[(size_t)(r0 + ty + j) * cols + c0 + tx];
  __syncthreads();
#pragma unroll
  for (int j = 0; j < 32; j += 8)
    out[(size_t)(c0 + ty + j) * rows + r0 + tx] = f2bf(tile[tx][ty + j]);
}

// ------- lora_mid + x->bf16 fused: lmid[m][r] = sum_k x[m][k]*a_down[idx][k][r]; Xb = bf16(x)
__global__ __launch_bounds__(256) void lora_mid_convert_kernel(const float* __restrict__ x,
                                                               const float* __restrict__ a_down,
                                                               const int* __restrict__ idxp,
                                                               float* __restrict__ lmid,
                                                               unsigned short* __restrict__ Xb) {
  __shared__ float ad[1024 * 9];
  const float* A = a_down + (size_t)(*idxp) * (1024 * 8);
  int t = threadIdx.x;
  for (int i = t; i < 8192; i += 256) ad[(i >> 3) * 9 + (i & 7)] = A[i];
  __syncthreads();
  int wid = t >> 6, lane = t & 63;
  int row = blockIdx.x * 4 + wid;
  const float* xr = x + (size_t)row * 1024;
  unsigned short* xbr = Xb + (size_t)row * 1024;
  float acc[8] = {0.f, 0.f, 0.f, 0.f, 0.f, 0.f, 0.f, 0.f};
  for (int i = 0; i < 16; ++i) {
    int k = i * 64 + lane;
    float xv = xr[k];
    xbr[k] = f2bf(xv);
#pragma unroll
    for (int r = 0; r < 8; ++r) acc[r] += xv * ad[k * 9 + r];
  }
#pragma unroll
  for (int off = 32; off > 0; off >>= 1) {
#pragma unroll
    for (int r = 0; r < 8; ++r) acc[r] += __shfl_xor(acc[r], off);
  }
  if (lane == 0) {
    *(float4*)(lmid + (size_t)row * 8) = make_float4(acc[0], acc[1], acc[2], acc[3]);
    *(float4*)(lmid + (size_t)row * 8 + 4) = make_float4(acc[4], acc[5], acc[6], acc[7]);
  }
}

// ===== 128x128 GEMM (BK=32, 4 waves) + 3-buffer rotating pipeline (48 KiB LDS), T3+T4:
//   prologue: stage T0->buf0, T1->buf1, vmcnt(4) (T0 landed), barrier.
//   iter kt:  stage T(kt+2) -> buf[(kt+2)%3]  (that buffer's readers finished before the
//             end-of-(kt-1) barrier; its prior writes drained 2 steps ago -> race-free),
//             ds_read frags + 16 MFMA from buf[kt%3],
//             vmcnt(4): drains exactly T(kt+1) (in flight a full K-step + compute, ~1000+cyc),
//             barrier. Tail (no stage): vmcnt(0) at kt=NKT-2.
//   Counted vmcnt is never 0 in steady state (T4) -- the R8 vmcnt(0)-per-step exposed
//   200-900cyc of L2/HBM latency each K-step (MfmaUtil 17%).
//   LDS swizzle + XCD-square mapping unchanged (proven R7/R8).
template <int LD, int NKT>
static __device__ __forceinline__ void gemm_kloop3(const unsigned short* __restrict__ A,
                                                   const unsigned short* __restrict__ B,
                                                   size_t m0, size_t n0, char* smem,
                                                   floatx4 (&acc)[4][4]) {
  const int t = threadIdx.x;
  const int wid = t >> 6, lane = t & 63;
  const int wr = wid >> 1, wc = wid & 1;
  const int lr = lane & 15, kg = lane >> 4;
  const int kgx = kg ^ ((lr >> 1) & 3);
  const int srow = t >> 2, scol = ((t & 3) ^ ((t >> 3) & 3)) * 8;
  const unsigned short* gA0 = A + (m0 + srow) * LD + scol;
  const unsigned short* gA1 = A + (m0 + 64 + srow) * LD + scol;
  const unsigned short* gB0 = B + (n0 + srow) * LD + scol;
  const unsigned short* gB1 = B + (n0 + 64 + srow) * LD + scol;
  const unsigned ldsOff = (unsigned)(wid << 10);

#define STAGE(bufb, ko)                           \
  do {                                            \
    char* lA_ = smem + (bufb) + ldsOff;           \
    char* lB_ = smem + (bufb) + 8192 + ldsOff;    \
    gload16(gA0 + (ko), lA_);                     \
    gload16(gA1 + (ko), lA_ + 4096);              \
    gload16(gB0 + (ko), lB_);                     \
    gload16(gB1 + (ko), lB_ + 4096);              \
  } while (0)

  // prologue: T0 -> buf0, T1 -> buf1; drain T0 (leave T1's 4 in flight)
  STAGE(0u, 0);
  STAGE(16384u, 32);
  WAIT_VM(4);
  S_BARRIER();

  unsigned cur = 0u, stg = 32768u;
#pragma unroll 1
  for (int kt = 0; kt < NKT; ++kt) {
    if (kt + 2 < NKT) STAGE(stg, (kt + 2) * 32);
    const unsigned short* As = (const unsigned short*)(smem + cur);
    const unsigned short* Bs = (const unsigned short*)(smem + cur + 8192);
    bfloatx8 af[4], bfv[4];
#pragma unroll
    for (int mi = 0; mi < 4; ++mi)
      af[mi] = *(const bfloatx8*)(As + (wr * 64 + mi * 16 + lr) * 32 + kgx * 8);
#pragma unroll
    for (int ni = 0; ni < 4; ++ni)
      bfv[ni] = *(const bfloatx8*)(Bs + (wc * 64 + ni * 16 + lr) * 32 + kgx * 8);
#pragma unroll
    for (int mi = 0; mi < 4; ++mi) {
#pragma unroll
      for (int ni = 0; ni < 4; ++ni)
        acc[mi][ni] = __builtin_amdgcn_mfma_f32_16x16x32_bf16(af[mi], bfv[ni], acc[mi][ni], 0, 0, 0);
    }
    if (kt + 2 < NKT) { WAIT_VM(4); } else { WAIT_VM(0); }
    S_BARRIER();
    cur = (cur == 32768u) ? 0u : cur + 16384u;
    stg = (stg == 32768u) ? 0u : stg + 16384u;
  }
#undef STAGE
}

// ------------- GEMM1: H[m][f] = gelu( Xb . W1T^T + b1 ), bf16 out. grid 4096 -------------
__global__ __launch_bounds__(256) void gemm1_gelu_kernel(const unsigned short* __restrict__ A,
                                                         const unsigned short* __restrict__ B,
                                                         const float* __restrict__ bias,
                                                         unsigned short* __restrict__ H) {
  __shared__ __align__(16) char smem[49152];
  const int t = threadIdx.x;
  const int wid = t >> 6, lane = t & 63;
  const int wr = wid >> 1, wc = wid & 1;
  const int lr = lane & 15, kg = lane >> 4;

  // XCD-square mapping: grid = 128(m) x 32(n); per XCD 8 squares of 8x8
  const int bid = blockIdx.x;
  const int xcd = bid & 7, j = bid >> 3;       // j 0..511
  const int sq = j >> 6, i = j & 63;           // sq 0..7
  const int mt = xcd * 16 + (sq & 1) * 8 + (i & 7);
  const int nt = (sq >> 1) * 8 + (i >> 3);
  const size_t m0 = (size_t)mt * 128;
  const size_t n0 = (size_t)nt * 128;

  floatx4 acc[4][4] = {};
  gemm_kloop3<1024, 32>(A, B, m0, n0, smem, acc);

  // epilogue (fully unrolled, rule #20): LDS transpose -> coalesced bf16 stores
  __syncthreads();
  float* sE = (float*)smem;  // 4096 f32
  const int row32 = t >> 3, col0 = (t & 7) * 16;
  const int stripe = row32 >> 4, lrow = row32 & 15;
#pragma unroll
  for (int mi = 0; mi < 4; ++mi) {
#pragma unroll
    for (int ni = 0; ni < 4; ++ni) {
#pragma unroll
      for (int r = 0; r < 4; ++r)
        sE[wr * 2048 + (kg * 4 + r) * 128 + wc * 64 + ni * 16 + lr] = acc[mi][ni][r];
    }
    __syncthreads();
    const size_t gm = m0 + stripe * 64 + mi * 16 + lrow;
    const float* src = sE + stripe * 2048 + lrow * 128 + col0;
    alignas(16) unsigned short pk[16];
#pragma unroll
    for (int i2 = 0; i2 < 16; ++i2) {
      float v = src[i2] + bias[n0 + col0 + i2];
      float g = 0.5f * v * (1.0f + erff(v * 0.70710678118654752440f));
      pk[i2] = f2bf(g);
    }
    *(ushortx8*)(H + gm * 4096 + n0 + col0) = *(const ushortx8*)&pk[0];
    *(ushortx8*)(H + gm * 4096 + n0 + col0 + 8) = *(const ushortx8*)&pk[8];
    __syncthreads();
  }
}

// ------------- GEMM2: OUT[m][d] = H . W2T^T + b2 + lora, f32 out. grid 1024 -------------
__global__ __launch_bounds__(256) void gemm2_out_kernel(const unsigned short* __restrict__ A,
                                                        const unsigned short* __restrict__ B,
                                                        const float* __restrict__ bias,
                                                        const float* __restrict__ lmid,
                                                        const float* __restrict__ a_up,
                                                        const int* __restrict__ idxp,
                                                        float* __restrict__ OUT) {
  __shared__ __align__(16) char smem[49152];
  const int t = threadIdx.x;
  const int wid = t >> 6, lane = t & 63;
  const int wr = wid >> 1, wc = wid & 1;
  const int lr = lane & 15, kg = lane >> 4;

  // XCD-square mapping: grid = 128(m) x 8(n); per XCD 2 squares of 8x8
  const int bid = blockIdx.x;
  const int xcd = bid & 7, j = bid >> 3;   // j 0..127
  const int sq = j >> 6, i = j & 63;       // sq 0..1
  const int mt = xcd * 16 + sq * 8 + (i & 7);
  const int nt = i >> 3;
  const size_t m0 = (size_t)mt * 128;
  const size_t n0 = (size_t)nt * 128;

  floatx4 acc[4][4] = {};
  gemm_kloop3<4096, 128>(A, B, m0, n0, smem, acc);

  // epilogue (fully unrolled): LDS transpose -> coalesced f32 stores + bias + LoRA
  __syncthreads();
  float* sE = (float*)smem;
  const float* aup = a_up + (size_t)(*idxp) * 8192;
  const int row32 = t >> 3, col0 = (t & 7) * 16;
  const int stripe = row32 >> 4, lrow = row32 & 15;
#pragma unroll
  for (int mi = 0; mi < 4; ++mi) {
#pragma unroll
    for (int ni = 0; ni < 4; ++ni) {
#pragma unroll
      for (int r = 0; r < 4; ++r)
        sE[wr * 2048 + (kg * 4 + r) * 128 + wc * 64 + ni * 16 + lr] = acc[mi][ni][r];
    }
    __syncthreads();
    const size_t gm = m0 + stripe * 64 + mi * 16 + lrow;
    const float* src = sE + stripe * 2048 + lrow * 128 + col0;
    alignas(16) float lmv[8];
    *(float4*)&lmv[0] = *(const float4*)(lmid + gm * 8);
    *(float4*)&lmv[4] = *(const float4*)(lmid + gm * 8 + 4);
    alignas(16) float v[16];
#pragma unroll
    for (int i2 = 0; i2 < 16; ++i2) v[i2] = src[i2] + bias[n0 + col0 + i2];
#pragma unroll
    for (int r = 0; r < 8; ++r) {
      const float lw = lmv[r];
      const float* ar = aup + r * 1024 + n0 + col0;
#pragma unroll
      for (int i2 = 0; i2 < 16; ++i2) v[i2] += lw * ar[i2];
    }
#pragma unroll
    for (int i2 = 0; i2 < 16; i2 += 4)
      *(float4*)(OUT + gm * 1024 + n0 + col0 + i2) = *(const float4*)&v[i2];
    __syncthreads();
  }
}

extern "C" void kernel_launch(void* const* d_in, const int* in_sizes, int n_in,
                              void* d_out, int out_size, void* d_ws, size_t ws_size,
                              hipStream_t stream) {
  const float* x      = (const float*)d_in[0];
  const float* w1     = (const float*)d_in[1];
  const float* b1     = (const float*)d_in[2];
  const float* w2     = (const float*)d_in[3];
  const float* b2     = (const float*)d_in[4];
  const float* a_down = (const float*)d_in[5];
  const float* a_up   = (const float*)d_in[6];
  const int*   idx    = (const int*)d_in[7];
  float* out = (float*)d_out;

  char* ws = (char*)d_ws;
  unsigned short* Xb  = (unsigned short*)(ws);              // 16384x1024 bf16 = 32 MiB
  unsigned short* W1T = (unsigned short*)(ws + 33554432);   // 4096x1024 bf16 = 8 MiB
  unsigned short* W2T = (unsigned short*)(ws + 41943040);   // 1024x4096 bf16 = 8 MiB
  float*          LMID = (float*)(ws + 50331648);           // 16384x8 f32 = 0.5 MiB
  unsigned short* H   = (unsigned short*)(ws + 50855936);   // 16384x4096 bf16 = 128 MiB

  transpose_bf16_kernel<<<dim3(128, 32), dim3(32, 8), 0, stream>>>(w1, W1T, 1024, 4096);
  transpose_bf16_kernel<<<dim3(32, 128), dim3(32, 8), 0, stream>>>(w2, W2T, 4096, 1024);
  lora_mid_convert_kernel<<<4096, 256, 0, stream>>>(x, a_down, idx, LMID, Xb);
  gemm1_gelu_kernel<<<4096, 256, 0, stream>>>(Xb, W1T, b1, H);
  gemm2_out_kernel<<<1024, 256, 0, stream>>>(H, W2T, b2, LMID, a_up, idx, out);
}